// Round 3
// baseline (192.434 us; speedup 1.0000x reference)
//
#include <hip/hip_runtime.h>
#include <hip/hip_bf16.h>
#include <stdint.h>

typedef __bf16 bf16;
typedef __bf16 bf16x8 __attribute__((ext_vector_type(8)));
typedef __bf16 bf16x4 __attribute__((ext_vector_type(4)));
typedef __bf16 bf16x2 __attribute__((ext_vector_type(2)));
typedef float f32x4 __attribute__((ext_vector_type(4)));
typedef float f32x2 __attribute__((ext_vector_type(2)));
typedef int i32x4 __attribute__((ext_vector_type(4)));

#define GAS __attribute__((address_space(1)))
#define LAS __attribute__((address_space(3)))

#define NROIS 1000
#define DEPTH 256
#define CIN 320
#define KDIM 15680      // 320*49
#define TABS 120

// NHWC offsets (floats, within T region)
#define T_P2 0
#define T_P3 6553600
#define T_P4 8192000
#define T_P5 8601600
#define T_RNG 8704000

// ws byte offsets (aliased; stream-ordered):
//  TAB [0, 0.5M) | A [0.5M, 32.6M) | T [33M, 74.4M) dead after crop
//  part [33M, 97M) alias T (gemm1 runs after crop)
//  x1b [0.5M, 2.6M) alias A (A dead after gemm1); x2 [2.6M, 6.8M)
#define OFF_TAB  0ULL
#define OFF_A    524288ULL
#define OFF_T    34603008ULL
#define OFF_PART 34603008ULL
#define OFF_X1B  524288ULL
#define OFF_X2   2621440ULL

// ---------------- prep: CHW->HWC transpose + per-ROI tables (merged) ----------------
__global__ __launch_bounds__(256) void k_prep(const float* __restrict__ p2, const float* __restrict__ p3,
                                              const float* __restrict__ p4, const float* __restrict__ p5,
                                              const float* __restrict__ rng, float* __restrict__ T,
                                              const float* __restrict__ rois, float* __restrict__ tab) {
    __shared__ float tile[64][65];
    int bid = blockIdx.x, t = threadIdx.x;
    if (bid >= 2528) {   // roi table blocks
        int n = (bid - 2528) * 256 + t;
        if (n >= NROIS) return;
        float y1 = rois[n*4+0], x1 = rois[n*4+1], y2 = rois[n*4+2], x2 = rois[n*4+3];
        float h = __fsub_rn(y2, y1), w = __fsub_rn(x2, x1);
        float rl = 4.0f + logf(sqrtf(h * w) / (224.0f / 640.0f)) / logf(2.0f);
        int lvl = (int)rintf(rl);
        lvl = min(5, max(2, lvl));
        float* tt = tab + (size_t)n * TABS;
        tt[112] = (float)lvl;
        int Hs0 = 160 >> (lvl - 2);
        for (int g = 0; g < 2; g++) {
            int H = g ? 160 : Hs0;
            float* tg = tt + g * 56;
            float fH = (float)(H - 1);
            float a = __fmul_rn(y1, fH);
            float s = __fdiv_rn(__fmul_rn(h, fH), 6.0f);
            for (int i = 0; i < 7; i++) {
                float iny = __fadd_rn(a, __fmul_rn((float)i, s));
                float tp = floorf(iny), bt = ceilf(iny);
                tg[i]      = (float)min(H-1, max(0, (int)tp));
                tg[7 + i]  = (float)min(H-1, max(0, (int)bt));
                tg[14 + i] = iny - tp;
                tg[21 + i] = (iny >= 0.0f && iny <= fH) ? 1.0f : 0.0f;
            }
            a = __fmul_rn(x1, fH);
            s = __fdiv_rn(__fmul_rn(w, fH), 6.0f);
            for (int j = 0; j < 7; j++) {
                float inx = __fadd_rn(a, __fmul_rn((float)j, s));
                float lf = floorf(inx), rt = ceilf(inx);
                tg[28 + j] = (float)min(H-1, max(0, (int)lf));
                tg[35 + j] = (float)min(H-1, max(0, (int)rt));
                tg[42 + j] = inx - lf;
                tg[49 + j] = (inx >= 0.0f && inx <= fH) ? 1.0f : 0.0f;
            }
        }
        return;
    }
    const float* src; float* dst; int C, X, loc;
    if (bid < 1600)      { src = p2;  dst = T + T_P2;  C = 256; X = 25600; loc = bid; }
    else if (bid < 2000) { src = p3;  dst = T + T_P3;  C = 256; X = 6400;  loc = bid - 1600; }
    else if (bid < 2100) { src = p4;  dst = T + T_P4;  C = 256; X = 1600;  loc = bid - 2000; }
    else if (bid < 2128) { src = p5;  dst = T + T_P5;  C = 256; X = 400;   loc = bid - 2100; }
    else                 { src = rng; dst = T + T_RNG; C = 64;  X = 25600; loc = bid - 2128; }
    int xtiles = (X + 63) >> 6;
    int xt = loc % xtiles, ct = loc / xtiles;
    int x0 = xt << 6, c0 = ct << 6;
    #pragma unroll
    for (int r = 0; r < 16; r++) {
        int lin = r * 256 + t;
        int lc = lin >> 6, lx = lin & 63;
        int x = x0 + lx;
        tile[lc][lx] = (x < X) ? src[(size_t)(c0 + lc) * X + x] : 0.0f;
    }
    __syncthreads();
    #pragma unroll
    for (int r = 0; r < 16; r++) {
        int lin = r * 256 + t;
        int lxx = lin >> 6, lcc = lin & 63;
        int x = x0 + lxx;
        if (x < X) dst[(size_t)x * C + c0 + lcc] = tile[lcc][lxx];
    }
}

// ---------------- crop_and_resize from NHWC ----------------
#define RES_S 329
__global__ __launch_bounds__(256) void k_crop2(const float* __restrict__ T, const float* __restrict__ tab,
                                               float* __restrict__ out_rf, bf16* __restrict__ A) {
    int n = blockIdx.x, t = threadIdx.x;
    if (n >= NROIS) {                 // zero-pad A rows 1000..1023
        i32x4* row = (i32x4*)(A + (size_t)n * KDIM);
        for (int i = t; i < KDIM * 2 / 16; i += 256) row[i] = i32x4{0,0,0,0};
        return;
    }
    __shared__ float res[49 * RES_S];
    __shared__ float tl_[TABS];
    if (t < TABS) tl_[t] = tab[(size_t)n * TABS + t];
    __syncthreads();
    int lvl = (int)tl_[112];
    int H = 160 >> (lvl - 2);
    int toff = (lvl == 2) ? T_P2 : (lvl == 3) ? T_P3 : (lvl == 4) ? T_P4 : T_P5;
    const float* F = T + toff;
    {
        int q = t & 63, pl = t >> 6, c4 = q * 4;
        for (int g = 0; g < 13; g++) {
            int pos = g * 4 + pl;
            if (pos < 49) {
                int i = pos / 7, j = pos % 7;
                int ti = (int)tl_[i],      bi = (int)tl_[7 + i];
                int li = (int)tl_[28 + j], ri = (int)tl_[35 + j];
                float ly = tl_[14 + i], lx = tl_[42 + j];
                float valid = tl_[21 + i] * tl_[49 + j];
                f32x4 vtl = *(const f32x4*)(F + (size_t)(ti * H + li) * 256 + c4);
                f32x4 vtr = *(const f32x4*)(F + (size_t)(ti * H + ri) * 256 + c4);
                f32x4 vbl = *(const f32x4*)(F + (size_t)(bi * H + li) * 256 + c4);
                f32x4 vbr = *(const f32x4*)(F + (size_t)(bi * H + ri) * 256 + c4);
                f32x4 top = vtl + (vtr - vtl) * lx;
                f32x4 bot = vbl + (vbr - vbl) * lx;
                f32x4 v = top + (bot - top) * ly;
                if (valid == 0.0f) v = f32x4{0.f,0.f,0.f,0.f};
                *(f32x4*)(&res[pos * RES_S + c4]) = v;
            }
        }
    }
    {
        int q = t & 15, pl = t >> 4, c4 = q * 4;
        const float* R = T + T_RNG;
        for (int g = 0; g < 4; g++) {
            int pos = g * 16 + pl;
            if (pos < 49) {
                int i = pos / 7, j = pos % 7;
                int ti = (int)tl_[56 + i], bi = (int)tl_[63 + i];
                int li = (int)tl_[84 + j], ri = (int)tl_[91 + j];
                float ly = tl_[70 + i], lx = tl_[98 + j];
                float valid = tl_[77 + i] * tl_[105 + j];
                f32x4 vtl = *(const f32x4*)(R + (size_t)(ti * 160 + li) * 64 + c4);
                f32x4 vtr = *(const f32x4*)(R + (size_t)(ti * 160 + ri) * 64 + c4);
                f32x4 vbl = *(const f32x4*)(R + (size_t)(bi * 160 + li) * 64 + c4);
                f32x4 vbr = *(const f32x4*)(R + (size_t)(bi * 160 + ri) * 64 + c4);
                f32x4 top = vtl + (vtr - vtl) * lx;
                f32x4 bot = vbl + (vbr - vbl) * lx;
                f32x4 v = top + (bot - top) * ly;
                if (valid == 0.0f) v = f32x4{0.f,0.f,0.f,0.f};
                *(f32x4*)(&res[pos * RES_S + 256 + c4]) = v;
            }
        }
    }
    __syncthreads();
    size_t ob = (size_t)n * KDIM;
    for (int k = 0; k < 31; k++) {
        int i2 = (k * 256 + t) * 2;
        if (i2 < KDIM) {
            float e0 = res[(i2 % 49) * RES_S + i2 / 49];
            int i3 = i2 + 1;
            float e1 = res[(i3 % 49) * RES_S + i3 / 49];
            *(f32x2*)(out_rf + ob + i2) = f32x2{e0, e1};
            bf16x2 b2; b2[0] = (bf16)e0; b2[1] = (bf16)e1;
            *(bf16x2*)(A + ob + i2) = b2;
        }
    }
}

// ---------------- 256x128 MFMA GEMM, A bf16 (gload_lds, swizzled), B f32 (reg->cvt->ds_write) ----
// C = A(MxK) * B(NxK)^T -> part[z] (1024x1024 f32 slices)
template<int REMAP>
__global__ __launch_bounds__(512, 4) void k_gemm256(const bf16* __restrict__ A, const float* __restrict__ Bf,
                                                    float* __restrict__ part, int K,
                                                    int steps_base, int steps_rem) {
    __shared__ bf16 sA[256 * 64];
    __shared__ bf16 sB[128 * 64];
    int tid = threadIdx.x;
    int l = tid & 63, w = tid >> 6;
    int bx, by, bz;
    if (REMAP) {
        // 512 blocks: id = xcd + 8*(x + 4*gHi); group g = gHi*8+xcd -> (y,z).
        // All 4 x-blocks of a (y,z) group land on one XCD (B-slice L2-resident).
        int id = blockIdx.x;
        int xcd = id & 7, slot = id >> 3;
        bx = slot & 3;
        int g = (slot >> 2) * 8 + xcd;
        by = g & 7; bz = g >> 3;
    } else {
        bx = blockIdx.x; by = blockIdx.y; bz = blockIdx.z;
    }
    int tm = bx * 256, tn = by * 128;
    int s0 = bz * steps_base + min(bz, steps_rem);
    int ns = steps_base + (bz < steps_rem ? 1 : 0);
    int kend = s0 + ns;

    // A staging: wave w covers rows w*32+q*8+(l>>3); source col pre-swizzled so
    // linear gload_lds dest yields slot-XOR layout (rule #21: swz source + swz read).
    int lr8 = l >> 3;
    int srcoffA = ((l & 7) ^ lr8) << 3;
    const bf16* Abase = A + (size_t)(tm + w * 32 + lr8) * K + srcoffA;
    // B staging: thread -> row br = tid&127, quarter bh = tid>>7, 16 f32 cols
    int br = tid & 127, bh = tid >> 7;
    const float* Bbase = Bf + (size_t)(tn + br) * K + bh * 16;
    bf16* sBw0 = sB + br * 64 + (((bh * 2)     ^ (br & 7)) << 3);
    bf16* sBw1 = sB + br * 64 + (((bh * 2 + 1) ^ (br & 7)) << 3);

    int lr = l & 15, lh = l >> 4;
    int wm = (w >> 1) * 64, wn = (w & 1) * 64;
    int swz = l & 7;

    f32x4 acc[4][4] = {};

    bf16x8 cur0, cur1;
    {   // prologue: load+cvt B(s0)
        const float* p = Bbase + (size_t)s0 * 64;
        f32x4 t0 = *(const f32x4*)(p);
        f32x4 t1 = *(const f32x4*)(p + 4);
        f32x4 t2 = *(const f32x4*)(p + 8);
        f32x4 t3 = *(const f32x4*)(p + 12);
        #pragma unroll
        for (int e = 0; e < 4; e++) {
            cur0[e] = (bf16)t0[e]; cur0[4+e] = (bf16)t1[e];
            cur1[e] = (bf16)t2[e]; cur1[4+e] = (bf16)t3[e];
        }
    }
    for (int t = s0; t < kend; t++) {
        int kc = t * 64;
        #pragma unroll
        for (int q = 0; q < 4; q++)
            __builtin_amdgcn_global_load_lds((const GAS void*)(Abase + (size_t)(q * 8) * K + kc),
                                             (LAS void*)(sA + (w * 32 + q * 8) * 64), 16, 0, 0);
        *(bf16x8*)sBw0 = cur0;
        *(bf16x8*)sBw1 = cur1;
        {   // prefetch+cvt B(t+1) (clamped re-read on last iter; regs reused)
            int kn = (t + 1 < kend) ? (kc + 64) : kc;
            const float* p = Bbase + kn;
            f32x4 t0 = *(const f32x4*)(p);
            f32x4 t1 = *(const f32x4*)(p + 4);
            f32x4 t2 = *(const f32x4*)(p + 8);
            f32x4 t3 = *(const f32x4*)(p + 12);
            #pragma unroll
            for (int e = 0; e < 4; e++) {
                cur0[e] = (bf16)t0[e]; cur0[4+e] = (bf16)t1[e];
                cur1[e] = (bf16)t2[e]; cur1[4+e] = (bf16)t3[e];
            }
        }
        __syncthreads();
        #pragma unroll
        for (int ks2 = 0; ks2 < 2; ks2++) {
            int slot = ((ks2 * 4 + lh) ^ swz) << 3;
            bf16x8 af[4], bfr[4];
            #pragma unroll
            for (int mi = 0; mi < 4; mi++)
                af[mi] = *(const bf16x8*)(sA + (wm + mi * 16 + lr) * 64 + slot);
            #pragma unroll
            for (int ni = 0; ni < 4; ni++)
                bfr[ni] = *(const bf16x8*)(sB + (wn + ni * 16 + lr) * 64 + slot);
            #pragma unroll
            for (int mi = 0; mi < 4; mi++)
                #pragma unroll
                for (int ni = 0; ni < 4; ni++)
                    acc[mi][ni] = __builtin_amdgcn_mfma_f32_16x16x32_bf16(af[mi], bfr[ni], acc[mi][ni], 0, 0, 0);
        }
        __syncthreads();
    }
    float* pc = part + ((size_t)bz << 20);
    #pragma unroll
    for (int mi = 0; mi < 4; mi++)
        #pragma unroll
        for (int ni = 0; ni < 4; ni++)
            #pragma unroll
            for (int r = 0; r < 4; r++)
                pc[(size_t)(tm + wm + mi * 16 + lh * 4 + r) * 1024 + (tn + wn + ni * 16 + lr)] = acc[mi][ni][r];
}

// ---------------- reduce split-K(16) + bias + BN + ReLU -> bf16 (x1) ----------------
__global__ void k_reduce1(const float* __restrict__ part, const float* __restrict__ bias,
                          const float* __restrict__ gam, const float* __restrict__ bet,
                          const float* __restrict__ mu, const float* __restrict__ var,
                          bf16* __restrict__ x1b) {
    int idx = blockIdx.x * 256 + threadIdx.x;
    int n = idx >> 8;
    int o = (idx & 255) << 2;
    f32x4 v = {};
    #pragma unroll
    for (int s = 0; s < 16; s++) v += *(const f32x4*)(part + ((size_t)s << 20) + (size_t)n * 1024 + o);
    f32x4 b4 = *(const f32x4*)(bias + o);
    f32x4 g4 = *(const f32x4*)(gam + o);
    f32x4 e4 = *(const f32x4*)(bet + o);
    f32x4 m4 = *(const f32x4*)(mu + o);
    f32x4 v4 = *(const f32x4*)(var + o);
    bf16x4 ov;
    #pragma unroll
    for (int e = 0; e < 4; e++) {
        float sc = g4[e] / sqrtf(v4[e] + 0.001f);
        float y = (v[e] + b4[e] - m4[e]) * sc + e4[e];
        y = fmaxf(y, 0.0f);
        if (n >= NROIS) y = 0.0f;
        ov[e] = (bf16)y;
    }
    *(bf16x4*)(x1b + (size_t)n * 1024 + o) = ov;
}

// ---------------- reduce split-K(4) + bias + BN + ReLU -> f32 (x2) ----------------
__global__ void k_reduce2(const float* __restrict__ part, const float* __restrict__ bias,
                          const float* __restrict__ gam, const float* __restrict__ bet,
                          const float* __restrict__ mu, const float* __restrict__ var,
                          float* __restrict__ x2) {
    int idx = blockIdx.x * 256 + threadIdx.x;
    int n = idx >> 8;
    int o = (idx & 255) << 2;
    f32x4 v = {};
    #pragma unroll
    for (int s = 0; s < 4; s++) v += *(const f32x4*)(part + ((size_t)s << 20) + (size_t)n * 1024 + o);
    f32x4 b4 = *(const f32x4*)(bias + o);
    f32x4 g4 = *(const f32x4*)(gam + o);
    f32x4 e4 = *(const f32x4*)(bet + o);
    f32x4 m4 = *(const f32x4*)(mu + o);
    f32x4 v4 = *(const f32x4*)(var + o);
    f32x4 ov;
    #pragma unroll
    for (int e = 0; e < 4; e++) {
        float sc = g4[e] / sqrtf(v4[e] + 0.001f);
        float y = (v[e] + b4[e] - m4[e]) * sc + e4[e];
        ov[e] = fmaxf(y, 0.0f);
    }
    *(f32x4*)(x2 + (size_t)n * 1024 + o) = ov;
}

// ---------------- heads ----------------
__device__ __forceinline__ float wred(float v) {
    #pragma unroll
    for (int off = 32; off; off >>= 1) v += __shfl_xor(v, off);
    return v;
}

__global__ void k_heads(const float* __restrict__ x2,
                        const float* __restrict__ wc, const float* __restrict__ bc,
                        const float* __restrict__ wb, const float* __restrict__ bb,
                        const float* __restrict__ wp, const float* __restrict__ bp,
                        float* __restrict__ out) {
    int w = threadIdx.x >> 6, l = threadIdx.x & 63;
    int n = blockIdx.x * 4 + w;
    float ac0 = 0.f, ac1 = 0.f, ab[8] = {}, ap[6] = {};
    const float* xr = x2 + (size_t)n * 1024;
    for (int kk = 0; kk < 16; kk++) {
        int k = kk * 64 + l;
        float xv = xr[k];
        ac0 += xv * wc[k];
        ac1 += xv * wc[1024 + k];
        #pragma unroll
        for (int o = 0; o < 8; o++) ab[o] += xv * wb[o * 1024 + k];
        #pragma unroll
        for (int o = 0; o < 6; o++) ap[o] += xv * wp[o * 1024 + k];
    }
    ac0 = wred(ac0); ac1 = wred(ac1);
    #pragma unroll
    for (int o = 0; o < 8; o++) ab[o] = wred(ab[o]);
    #pragma unroll
    for (int o = 0; o < 6; o++) ap[o] = wred(ap[o]);
    if (l == 0) {
        float l0 = ac0 + bc[0], l1 = ac1 + bc[1];
        out[n * 2] = l0; out[n * 2 + 1] = l1;
        float m = fmaxf(l0, l1);
        float e0 = expf(l0 - m), e1 = expf(l1 - m);
        float inv = 1.0f / (e0 + e1);
        out[2000 + n * 2] = e0 * inv; out[2000 + n * 2 + 1] = e1 * inv;
        #pragma unroll
        for (int o = 0; o < 8; o++) out[4000 + n * 8 + o] = ab[o] + bb[o];
        #pragma unroll
        for (int o = 0; o < 6; o++) out[12000 + n * 6 + o] = ap[o] + bp[o];
    }
}

extern "C" void kernel_launch(void* const* d_in, const int* in_sizes, int n_in,
                              void* d_out, int out_size, void* d_ws, size_t ws_size,
                              hipStream_t stream) {
    const float* p2      = (const float*)d_in[0];
    const float* p3      = (const float*)d_in[1];
    const float* p4      = (const float*)d_in[2];
    const float* p5      = (const float*)d_in[3];
    const float* rois    = (const float*)d_in[4];
    const float* ranges  = (const float*)d_in[5];
    const float* conv1_w = (const float*)d_in[6];
    const float* conv1_b = (const float*)d_in[7];
    const float* bn1_g   = (const float*)d_in[8];
    const float* bn1_b   = (const float*)d_in[9];
    const float* bn1_m   = (const float*)d_in[10];
    const float* bn1_v   = (const float*)d_in[11];
    const float* conv2_w = (const float*)d_in[12];
    const float* conv2_b = (const float*)d_in[13];
    const float* bn2_g   = (const float*)d_in[14];
    const float* bn2_b   = (const float*)d_in[15];
    const float* bn2_m   = (const float*)d_in[16];
    const float* bn2_v   = (const float*)d_in[17];
    const float* wc      = (const float*)d_in[18];
    const float* bc      = (const float*)d_in[19];
    const float* wb      = (const float*)d_in[20];
    const float* bb      = (const float*)d_in[21];
    const float* wp      = (const float*)d_in[22];
    const float* bp      = (const float*)d_in[23];

    char* ws = (char*)d_ws;
    float* tab  = (float*)(ws + OFF_TAB);
    bf16*  A    = (bf16*)(ws + OFF_A);
    float* T    = (float*)(ws + OFF_T);
    float* part = (float*)(ws + OFF_PART);
    bf16*  x1b  = (bf16*)(ws + OFF_X1B);
    float* x2   = (float*)(ws + OFF_X2);
    float* out  = (float*)d_out;

    k_prep<<<2532, 256, 0, stream>>>(p2, p3, p4, p5, ranges, T, rois, tab);
    k_crop2<<<1024, 256, 0, stream>>>(T, tab, out + 18000, A);
    // GEMM1: M=1024(pad) x N=1024 x K=15680, 256x128 tiles, z=16 (245 steps: 15 base, rem 5)
    k_gemm256<1><<<512, 512, 0, stream>>>(A, conv1_w, part, 15680, 15, 5);
    k_reduce1<<<1024, 256, 0, stream>>>(part, conv1_b, bn1_g, bn1_b, bn1_m, bn1_v, x1b);
    // GEMM2: K=1024, z=4 (16 steps: 4 base)
    k_gemm256<0><<<dim3(4, 8, 4), 512, 0, stream>>>(x1b, conv2_w, part, 1024, 4, 0);
    k_reduce2<<<1024, 256, 0, stream>>>(part, conv2_b, bn2_g, bn2_b, bn2_m, bn2_v, x2);
    k_heads<<<250, 256, 0, stream>>>(x2, wc, bc, wb, bb, wp, bp, out);
}

// Round 4
// 184.688 us; speedup vs baseline: 1.0419x; 1.0419x over previous
//
#include <hip/hip_runtime.h>
#include <hip/hip_bf16.h>
#include <stdint.h>

typedef __bf16 bf16;
typedef __bf16 bf16x8 __attribute__((ext_vector_type(8)));
typedef __bf16 bf16x4 __attribute__((ext_vector_type(4)));
typedef __bf16 bf16x2 __attribute__((ext_vector_type(2)));
typedef float f32x4 __attribute__((ext_vector_type(4)));
typedef float f32x2 __attribute__((ext_vector_type(2)));
typedef int i32x4 __attribute__((ext_vector_type(4)));

#define GAS __attribute__((address_space(1)))
#define LAS __attribute__((address_space(3)))

#define NROIS 1000
#define DEPTH 256
#define CIN 320
#define KDIM 15680      // 320*49
#define TABS 120

// NHWC offsets (floats, within T region)
#define T_P2 0
#define T_P3 6553600
#define T_P4 8192000
#define T_P5 8601600
#define T_RNG 8704000

// ws layout (aliased; stream-ordered):
//  TAB [0, 0.5M) | A [0.5M, 32.6M) | T [33M, 74.4M) dead after crop
//  part [33M, 65M) alias T (z=8, gemm1 runs after crop)
//  x1b [0.5M, 2.6M) alias A (A dead after gemm1); x2 [2.6M, 6.8M)
#define OFF_TAB  0ULL
#define OFF_A    524288ULL
#define OFF_T    34603008ULL
#define OFF_PART 34603008ULL
#define OFF_X1B  524288ULL
#define OFF_X2   2621440ULL

// ---------------- prep: CHW->HWC transpose + per-ROI tables (merged) ----------------
__global__ __launch_bounds__(256) void k_prep(const float* __restrict__ p2, const float* __restrict__ p3,
                                              const float* __restrict__ p4, const float* __restrict__ p5,
                                              const float* __restrict__ rng, float* __restrict__ T,
                                              const float* __restrict__ rois, float* __restrict__ tab) {
    __shared__ float tile[64][65];
    int bid = blockIdx.x, t = threadIdx.x;
    if (bid >= 2528) {   // roi table blocks
        int n = (bid - 2528) * 256 + t;
        if (n >= NROIS) return;
        float y1 = rois[n*4+0], x1 = rois[n*4+1], y2 = rois[n*4+2], x2 = rois[n*4+3];
        float h = __fsub_rn(y2, y1), w = __fsub_rn(x2, x1);
        float rl = 4.0f + logf(sqrtf(h * w) / (224.0f / 640.0f)) / logf(2.0f);
        int lvl = (int)rintf(rl);
        lvl = min(5, max(2, lvl));
        float* tt = tab + (size_t)n * TABS;
        tt[112] = (float)lvl;
        int Hs0 = 160 >> (lvl - 2);
        for (int g = 0; g < 2; g++) {
            int H = g ? 160 : Hs0;
            float* tg = tt + g * 56;
            float fH = (float)(H - 1);
            float a = __fmul_rn(y1, fH);
            float s = __fdiv_rn(__fmul_rn(h, fH), 6.0f);
            for (int i = 0; i < 7; i++) {
                float iny = __fadd_rn(a, __fmul_rn((float)i, s));
                float tp = floorf(iny), bt = ceilf(iny);
                tg[i]      = (float)min(H-1, max(0, (int)tp));
                tg[7 + i]  = (float)min(H-1, max(0, (int)bt));
                tg[14 + i] = iny - tp;
                tg[21 + i] = (iny >= 0.0f && iny <= fH) ? 1.0f : 0.0f;
            }
            a = __fmul_rn(x1, fH);
            s = __fdiv_rn(__fmul_rn(w, fH), 6.0f);
            for (int j = 0; j < 7; j++) {
                float inx = __fadd_rn(a, __fmul_rn((float)j, s));
                float lf = floorf(inx), rt = ceilf(inx);
                tg[28 + j] = (float)min(H-1, max(0, (int)lf));
                tg[35 + j] = (float)min(H-1, max(0, (int)rt));
                tg[42 + j] = inx - lf;
                tg[49 + j] = (inx >= 0.0f && inx <= fH) ? 1.0f : 0.0f;
            }
        }
        return;
    }
    const float* src; float* dst; int C, X, loc;
    if (bid < 1600)      { src = p2;  dst = T + T_P2;  C = 256; X = 25600; loc = bid; }
    else if (bid < 2000) { src = p3;  dst = T + T_P3;  C = 256; X = 6400;  loc = bid - 1600; }
    else if (bid < 2100) { src = p4;  dst = T + T_P4;  C = 256; X = 1600;  loc = bid - 2000; }
    else if (bid < 2128) { src = p5;  dst = T + T_P5;  C = 256; X = 400;   loc = bid - 2100; }
    else                 { src = rng; dst = T + T_RNG; C = 64;  X = 25600; loc = bid - 2128; }
    int xtiles = (X + 63) >> 6;
    int xt = loc % xtiles, ct = loc / xtiles;
    int x0 = xt << 6, c0 = ct << 6;
    #pragma unroll
    for (int r = 0; r < 16; r++) {
        int lin = r * 256 + t;
        int lc = lin >> 6, lx = lin & 63;
        int x = x0 + lx;
        tile[lc][lx] = (x < X) ? src[(size_t)(c0 + lc) * X + x] : 0.0f;
    }
    __syncthreads();
    #pragma unroll
    for (int r = 0; r < 16; r++) {
        int lin = r * 256 + t;
        int lxx = lin >> 6, lcc = lin & 63;
        int x = x0 + lxx;
        if (x < X) dst[(size_t)x * C + c0 + lcc] = tile[lcc][lxx];
    }
}

// ---------------- crop_and_resize from NHWC ----------------
#define RES_S 329
__global__ __launch_bounds__(256) void k_crop2(const float* __restrict__ T, const float* __restrict__ tab,
                                               float* __restrict__ out_rf, bf16* __restrict__ A) {
    int n = blockIdx.x, t = threadIdx.x;
    if (n >= NROIS) {                 // zero-pad A rows 1000..1023
        i32x4* row = (i32x4*)(A + (size_t)n * KDIM);
        for (int i = t; i < KDIM * 2 / 16; i += 256) row[i] = i32x4{0,0,0,0};
        return;
    }
    __shared__ float res[49 * RES_S];
    __shared__ float tl_[TABS];
    if (t < TABS) tl_[t] = tab[(size_t)n * TABS + t];
    __syncthreads();
    int lvl = (int)tl_[112];
    int H = 160 >> (lvl - 2);
    int toff = (lvl == 2) ? T_P2 : (lvl == 3) ? T_P3 : (lvl == 4) ? T_P4 : T_P5;
    const float* F = T + toff;
    {
        int q = t & 63, pl = t >> 6, c4 = q * 4;
        for (int g = 0; g < 13; g++) {
            int pos = g * 4 + pl;
            if (pos < 49) {
                int i = pos / 7, j = pos % 7;
                int ti = (int)tl_[i],      bi = (int)tl_[7 + i];
                int li = (int)tl_[28 + j], ri = (int)tl_[35 + j];
                float ly = tl_[14 + i], lx = tl_[42 + j];
                float valid = tl_[21 + i] * tl_[49 + j];
                f32x4 vtl = *(const f32x4*)(F + (size_t)(ti * H + li) * 256 + c4);
                f32x4 vtr = *(const f32x4*)(F + (size_t)(ti * H + ri) * 256 + c4);
                f32x4 vbl = *(const f32x4*)(F + (size_t)(bi * H + li) * 256 + c4);
                f32x4 vbr = *(const f32x4*)(F + (size_t)(bi * H + ri) * 256 + c4);
                f32x4 top = vtl + (vtr - vtl) * lx;
                f32x4 bot = vbl + (vbr - vbl) * lx;
                f32x4 v = top + (bot - top) * ly;
                if (valid == 0.0f) v = f32x4{0.f,0.f,0.f,0.f};
                *(f32x4*)(&res[pos * RES_S + c4]) = v;
            }
        }
    }
    {
        int q = t & 15, pl = t >> 4, c4 = q * 4;
        const float* R = T + T_RNG;
        for (int g = 0; g < 4; g++) {
            int pos = g * 16 + pl;
            if (pos < 49) {
                int i = pos / 7, j = pos % 7;
                int ti = (int)tl_[56 + i], bi = (int)tl_[63 + i];
                int li = (int)tl_[84 + j], ri = (int)tl_[91 + j];
                float ly = tl_[70 + i], lx = tl_[98 + j];
                float valid = tl_[77 + i] * tl_[105 + j];
                f32x4 vtl = *(const f32x4*)(R + (size_t)(ti * 160 + li) * 64 + c4);
                f32x4 vtr = *(const f32x4*)(R + (size_t)(ti * 160 + ri) * 64 + c4);
                f32x4 vbl = *(const f32x4*)(R + (size_t)(bi * 160 + li) * 64 + c4);
                f32x4 vbr = *(const f32x4*)(R + (size_t)(bi * 160 + ri) * 64 + c4);
                f32x4 top = vtl + (vtr - vtl) * lx;
                f32x4 bot = vbl + (vbr - vbl) * lx;
                f32x4 v = top + (bot - top) * ly;
                if (valid == 0.0f) v = f32x4{0.f,0.f,0.f,0.f};
                *(f32x4*)(&res[pos * RES_S + 256 + c4]) = v;
            }
        }
    }
    __syncthreads();
    size_t ob = (size_t)n * KDIM;
    for (int k = 0; k < 31; k++) {
        int i2 = (k * 256 + t) * 2;
        if (i2 < KDIM) {
            float e0 = res[(i2 % 49) * RES_S + i2 / 49];
            int i3 = i2 + 1;
            float e1 = res[(i3 % 49) * RES_S + i3 / 49];
            *(f32x2*)(out_rf + ob + i2) = f32x2{e0, e1};
            bf16x2 b2; b2[0] = (bf16)e0; b2[1] = (bf16)e1;
            *(bf16x2*)(A + ob + i2) = b2;
        }
    }
}

// ---------------- 128x128 MFMA GEMM, double-buffered LDS, T3-minimum 2-phase ----------------
// A: bf16 MxK via global_load_lds (pre-swizzled source cols, XOR-swizzled reads)
// B: f32 NxK, 2-deep register prefetch -> cvt bf16 -> swizzled ds_write
// C = A * B^T -> part[z] (1024x1024 f32 slices)
template<int REMAP>
__global__ __launch_bounds__(256) void k_gemm128p(const bf16* __restrict__ A, const float* __restrict__ Bf,
                                                  float* __restrict__ part, int K,
                                                  int steps_base, int steps_rem) {
    __shared__ bf16 sA[2][128 * 64];
    __shared__ bf16 sB[2][128 * 64];
    int tid = threadIdx.x;
    int l = tid & 63, w = tid >> 6;
    int bx, by, bz;
    if (REMAP) {
        // 512 blocks: all 8 x-blocks of a (y,z) B-slice land on one XCD.
        int id = blockIdx.x;
        int xcd = id & 7, slot = id >> 3;
        bx = slot & 7;
        int g = (slot >> 3) * 8 + xcd;
        by = g & 7; bz = g >> 3;
    } else {
        bx = blockIdx.x; by = blockIdx.y; bz = blockIdx.z;
    }
    int tm = bx * 128, tn = by * 128;
    int s0 = bz * steps_base + min(bz, steps_rem);
    int ns = steps_base + (bz < steps_rem ? 1 : 0);
    int kend = s0 + ns;

    // A staging: wave w rows w*32+q*8+(l>>3); source col pre-swizzled (rule #21).
    int lr8 = l >> 3;
    const bf16* Abase = A + (size_t)(tm + w * 32 + lr8) * K + (((l & 7) ^ lr8) << 3);
    // B staging: thread -> row r = tid>>1, half h = tid&1 (32 f32 cols each)
    int brr = tid >> 1, bh = tid & 1;
    const float* Bbase = Bf + (size_t)(tn + brr) * K + bh * 32;
    int bswz = brr & 7;

    int lr = l & 15, lh = l >> 4;
    int wm = (w >> 1) * 64, wn = (w & 1) * 64;
    int swz = l & 7;

    f32x4 acc[4][4] = {};
    f32x4 breg[8];

#define LOADB(kc_) do { const float* p_ = Bbase + (kc_); \
        _Pragma("unroll") for (int e_ = 0; e_ < 8; e_++) breg[e_] = *(const f32x4*)(p_ + e_ * 4); } while (0)
#define STAGE(pb_, kc_) do { \
        _Pragma("unroll") for (int q_ = 0; q_ < 4; q_++) \
            __builtin_amdgcn_global_load_lds((const GAS void*)(Abase + (size_t)(q_ * 8) * K + (kc_)), \
                                             (LAS void*)(&sA[pb_][(w * 32 + q_ * 8) * 64]), 16, 0, 0); \
        _Pragma("unroll") for (int k_ = 0; k_ < 4; k_++) { \
            bf16x8 bb_; \
            _Pragma("unroll") for (int e_ = 0; e_ < 4; e_++) { \
                bb_[e_] = (bf16)breg[2 * k_][e_]; bb_[4 + e_] = (bf16)breg[2 * k_ + 1][e_]; } \
            *(bf16x8*)(&sB[pb_][brr * 64 + (((bh * 4 + k_) ^ bswz) << 3)]) = bb_; } } while (0)

    // prologue: stage tile s0, prefetch B(s0+1)
    LOADB((size_t)s0 * 64);
    STAGE(0, s0 * 64);
    LOADB((size_t)min(s0 + 1, kend - 1) * 64);
    __syncthreads();

    int p = 0;
    for (int t = s0; t < kend; t++) {
        if (t + 1 < kend) {
            STAGE(p ^ 1, (t + 1) * 64);
            LOADB((size_t)min(t + 2, kend - 1) * 64);
        }
        #pragma unroll
        for (int ks2 = 0; ks2 < 2; ks2++) {
            bf16x8 af[4], bfr[4];
            #pragma unroll
            for (int mi = 0; mi < 4; mi++) {
                int row = wm + mi * 16 + lr;
                af[mi] = *(const bf16x8*)(&sA[p][row * 64 + (((ks2 * 4 + lh) ^ (row & 7)) << 3)]);
            }
            #pragma unroll
            for (int ni = 0; ni < 4; ni++) {
                int row = wn + ni * 16 + lr;
                bfr[ni] = *(const bf16x8*)(&sB[p][row * 64 + (((ks2 * 4 + lh) ^ (row & 7)) << 3)]);
            }
            #pragma unroll
            for (int mi = 0; mi < 4; mi++)
                #pragma unroll
                for (int ni = 0; ni < 4; ni++)
                    acc[mi][ni] = __builtin_amdgcn_mfma_f32_16x16x32_bf16(af[mi], bfr[ni], acc[mi][ni], 0, 0, 0);
        }
        __syncthreads();
        p ^= 1;
    }
#undef LOADB
#undef STAGE
    float* pc = part + ((size_t)bz << 20);
    #pragma unroll
    for (int mi = 0; mi < 4; mi++)
        #pragma unroll
        for (int ni = 0; ni < 4; ni++)
            #pragma unroll
            for (int r = 0; r < 4; r++)
                pc[(size_t)(tm + wm + mi * 16 + lh * 4 + r) * 1024 + (tn + wn + ni * 16 + lr)] = acc[mi][ni][r];
}

// ---------------- reduce split-K(8) + bias + BN + ReLU -> bf16 (x1) ----------------
__global__ void k_reduce1(const float* __restrict__ part, const float* __restrict__ bias,
                          const float* __restrict__ gam, const float* __restrict__ bet,
                          const float* __restrict__ mu, const float* __restrict__ var,
                          bf16* __restrict__ x1b) {
    int idx = blockIdx.x * 256 + threadIdx.x;
    int n = idx >> 8;
    int o = (idx & 255) << 2;
    f32x4 v = {};
    #pragma unroll
    for (int s = 0; s < 8; s++) v += *(const f32x4*)(part + ((size_t)s << 20) + (size_t)n * 1024 + o);
    f32x4 b4 = *(const f32x4*)(bias + o);
    f32x4 g4 = *(const f32x4*)(gam + o);
    f32x4 e4 = *(const f32x4*)(bet + o);
    f32x4 m4 = *(const f32x4*)(mu + o);
    f32x4 v4 = *(const f32x4*)(var + o);
    bf16x4 ov;
    #pragma unroll
    for (int e = 0; e < 4; e++) {
        float sc = g4[e] / sqrtf(v4[e] + 0.001f);
        float y = (v[e] + b4[e] - m4[e]) * sc + e4[e];
        y = fmaxf(y, 0.0f);
        if (n >= NROIS) y = 0.0f;
        ov[e] = (bf16)y;
    }
    *(bf16x4*)(x1b + (size_t)n * 1024 + o) = ov;
}

// ---------------- reduce split-K(4) + bias + BN + ReLU -> f32 (x2) ----------------
__global__ void k_reduce2(const float* __restrict__ part, const float* __restrict__ bias,
                          const float* __restrict__ gam, const float* __restrict__ bet,
                          const float* __restrict__ mu, const float* __restrict__ var,
                          float* __restrict__ x2) {
    int idx = blockIdx.x * 256 + threadIdx.x;
    int n = idx >> 8;
    int o = (idx & 255) << 2;
    f32x4 v = {};
    #pragma unroll
    for (int s = 0; s < 4; s++) v += *(const f32x4*)(part + ((size_t)s << 20) + (size_t)n * 1024 + o);
    f32x4 b4 = *(const f32x4*)(bias + o);
    f32x4 g4 = *(const f32x4*)(gam + o);
    f32x4 e4 = *(const f32x4*)(bet + o);
    f32x4 m4 = *(const f32x4*)(mu + o);
    f32x4 v4 = *(const f32x4*)(var + o);
    f32x4 ov;
    #pragma unroll
    for (int e = 0; e < 4; e++) {
        float sc = g4[e] / sqrtf(v4[e] + 0.001f);
        float y = (v[e] + b4[e] - m4[e]) * sc + e4[e];
        ov[e] = fmaxf(y, 0.0f);
    }
    *(f32x4*)(x2 + (size_t)n * 1024 + o) = ov;
}

// ---------------- heads ----------------
__device__ __forceinline__ float wred(float v) {
    #pragma unroll
    for (int off = 32; off; off >>= 1) v += __shfl_xor(v, off);
    return v;
}

__global__ void k_heads(const float* __restrict__ x2,
                        const float* __restrict__ wc, const float* __restrict__ bc,
                        const float* __restrict__ wb, const float* __restrict__ bb,
                        const float* __restrict__ wp, const float* __restrict__ bp,
                        float* __restrict__ out) {
    int w = threadIdx.x >> 6, l = threadIdx.x & 63;
    int n = blockIdx.x * 4 + w;
    float ac0 = 0.f, ac1 = 0.f, ab[8] = {}, ap[6] = {};
    const float* xr = x2 + (size_t)n * 1024;
    for (int kk = 0; kk < 16; kk++) {
        int k = kk * 64 + l;
        float xv = xr[k];
        ac0 += xv * wc[k];
        ac1 += xv * wc[1024 + k];
        #pragma unroll
        for (int o = 0; o < 8; o++) ab[o] += xv * wb[o * 1024 + k];
        #pragma unroll
        for (int o = 0; o < 6; o++) ap[o] += xv * wp[o * 1024 + k];
    }
    ac0 = wred(ac0); ac1 = wred(ac1);
    #pragma unroll
    for (int o = 0; o < 8; o++) ab[o] = wred(ab[o]);
    #pragma unroll
    for (int o = 0; o < 6; o++) ap[o] = wred(ap[o]);
    if (l == 0) {
        float l0 = ac0 + bc[0], l1 = ac1 + bc[1];
        out[n * 2] = l0; out[n * 2 + 1] = l1;
        float m = fmaxf(l0, l1);
        float e0 = expf(l0 - m), e1 = expf(l1 - m);
        float inv = 1.0f / (e0 + e1);
        out[2000 + n * 2] = e0 * inv; out[2000 + n * 2 + 1] = e1 * inv;
        #pragma unroll
        for (int o = 0; o < 8; o++) out[4000 + n * 8 + o] = ab[o] + bb[o];
        #pragma unroll
        for (int o = 0; o < 6; o++) out[12000 + n * 6 + o] = ap[o] + bp[o];
    }
}

extern "C" void kernel_launch(void* const* d_in, const int* in_sizes, int n_in,
                              void* d_out, int out_size, void* d_ws, size_t ws_size,
                              hipStream_t stream) {
    const float* p2      = (const float*)d_in[0];
    const float* p3      = (const float*)d_in[1];
    const float* p4      = (const float*)d_in[2];
    const float* p5      = (const float*)d_in[3];
    const float* rois    = (const float*)d_in[4];
    const float* ranges  = (const float*)d_in[5];
    const float* conv1_w = (const float*)d_in[6];
    const float* conv1_b = (const float*)d_in[7];
    const float* bn1_g   = (const float*)d_in[8];
    const float* bn1_b   = (const float*)d_in[9];
    const float* bn1_m   = (const float*)d_in[10];
    const float* bn1_v   = (const float*)d_in[11];
    const float* conv2_w = (const float*)d_in[12];
    const float* conv2_b = (const float*)d_in[13];
    const float* bn2_g   = (const float*)d_in[14];
    const float* bn2_b   = (const float*)d_in[15];
    const float* bn2_m   = (const float*)d_in[16];
    const float* bn2_v   = (const float*)d_in[17];
    const float* wc      = (const float*)d_in[18];
    const float* bc      = (const float*)d_in[19];
    const float* wb      = (const float*)d_in[20];
    const float* bb      = (const float*)d_in[21];
    const float* wp      = (const float*)d_in[22];
    const float* bp      = (const float*)d_in[23];

    char* ws = (char*)d_ws;
    float* tab  = (float*)(ws + OFF_TAB);
    bf16*  A    = (bf16*)(ws + OFF_A);
    float* T    = (float*)(ws + OFF_T);
    float* part = (float*)(ws + OFF_PART);
    bf16*  x1b  = (bf16*)(ws + OFF_X1B);
    float* x2   = (float*)(ws + OFF_X2);
    float* out  = (float*)d_out;

    k_prep<<<2532, 256, 0, stream>>>(p2, p3, p4, p5, ranges, T, rois, tab);
    k_crop2<<<1024, 256, 0, stream>>>(T, tab, out + 18000, A);
    // GEMM1: M=1024(pad) x N=1024 x K=15680, 128x128 tiles, z=8 (245 steps: 30 base, rem 5)
    k_gemm128p<1><<<512, 256, 0, stream>>>(A, conv1_w, part, 15680, 30, 5);
    k_reduce1<<<1024, 256, 0, stream>>>(part, conv1_b, bn1_g, bn1_b, bn1_m, bn1_v, x1b);
    // GEMM2: K=1024, z=4 (16 steps: 4 base)
    k_gemm128p<0><<<dim3(8, 8, 4), 256, 0, stream>>>(x1b, conv2_w, part, 1024, 4, 0);
    k_reduce2<<<1024, 256, 0, stream>>>(part, conv2_b, bn2_g, bn2_b, bn2_m, bn2_v, x2);
    k_heads<<<250, 256, 0, stream>>>(x2, wc, bc, wb, bb, wp, bp, out);
}

// Round 5
// 164.858 us; speedup vs baseline: 1.1673x; 1.1203x over previous
//
#include <hip/hip_runtime.h>
#include <hip/hip_bf16.h>
#include <stdint.h>

typedef __bf16 bf16;
typedef __bf16 bf16x8 __attribute__((ext_vector_type(8)));
typedef __bf16 bf16x4 __attribute__((ext_vector_type(4)));
typedef __bf16 bf16x2 __attribute__((ext_vector_type(2)));
typedef float f32x4 __attribute__((ext_vector_type(4)));
typedef float f32x2 __attribute__((ext_vector_type(2)));
typedef int i32x4 __attribute__((ext_vector_type(4)));

#define GAS __attribute__((address_space(1)))
#define LAS __attribute__((address_space(3)))

#define NROIS 1000
#define DEPTH 256
#define CIN 320
#define KDIM 15680      // 320*49
#define KPAD 16128      // 252 K-tiles of 64; 14 z-slices x 18 tiles
#define TABS 120

// NHWC offsets (floats, within T region)
#define T_P2 0
#define T_P3 6553600
#define T_P4 8192000
#define T_P5 8601600
#define T_RNG 8704000

// ws layout (aliased; stream-ordered). Proven budget >= 100,401,152 B (R1).
//  A    [0, 33,030,144)                       live: crop -> gemm1
//  part [33,030,144, 91,750,400) 14 x 4MB     live: gemm1 -> reduce1 (and gemm2->reduce2)
//    tab [33,030,144, +480KB)  (inside part; dead before gemm1)
//    T   [33,554,432, +41.4MB) (inside part; dead before gemm1)
//  x1b  [0, 2MB) alias A        live: reduce1 -> gemm2
//  x2   [2,621,440, +4MB)       live: reduce2 -> heads
#define OFF_A    0ULL
#define OFF_PART 33030144ULL
#define OFF_TAB  33030144ULL
#define OFF_T    33554432ULL
#define OFF_X1B  0ULL
#define OFF_X2   2621440ULL

// ---------------- prep: CHW->HWC transpose + per-ROI tables (merged) ----------------
__global__ __launch_bounds__(256) void k_prep(const float* __restrict__ p2, const float* __restrict__ p3,
                                              const float* __restrict__ p4, const float* __restrict__ p5,
                                              const float* __restrict__ rng, float* __restrict__ T,
                                              const float* __restrict__ rois, float* __restrict__ tab) {
    __shared__ float tile[64][65];
    int bid = blockIdx.x, t = threadIdx.x;
    if (bid >= 2528) {   // roi table blocks
        int n = (bid - 2528) * 256 + t;
        if (n >= NROIS) return;
        float y1 = rois[n*4+0], x1 = rois[n*4+1], y2 = rois[n*4+2], x2 = rois[n*4+3];
        float h = __fsub_rn(y2, y1), w = __fsub_rn(x2, x1);
        float rl = 4.0f + logf(sqrtf(h * w) / (224.0f / 640.0f)) / logf(2.0f);
        int lvl = (int)rintf(rl);
        lvl = min(5, max(2, lvl));
        float* tt = tab + (size_t)n * TABS;
        tt[112] = (float)lvl;
        int Hs0 = 160 >> (lvl - 2);
        for (int g = 0; g < 2; g++) {
            int H = g ? 160 : Hs0;
            float* tg = tt + g * 56;
            float fH = (float)(H - 1);
            float a = __fmul_rn(y1, fH);
            float s = __fdiv_rn(__fmul_rn(h, fH), 6.0f);
            for (int i = 0; i < 7; i++) {
                float iny = __fadd_rn(a, __fmul_rn((float)i, s));
                float tp = floorf(iny), bt = ceilf(iny);
                tg[i]      = (float)min(H-1, max(0, (int)tp));
                tg[7 + i]  = (float)min(H-1, max(0, (int)bt));
                tg[14 + i] = iny - tp;
                tg[21 + i] = (iny >= 0.0f && iny <= fH) ? 1.0f : 0.0f;
            }
            a = __fmul_rn(x1, fH);
            s = __fdiv_rn(__fmul_rn(w, fH), 6.0f);
            for (int j = 0; j < 7; j++) {
                float inx = __fadd_rn(a, __fmul_rn((float)j, s));
                float lf = floorf(inx), rt = ceilf(inx);
                tg[28 + j] = (float)min(H-1, max(0, (int)lf));
                tg[35 + j] = (float)min(H-1, max(0, (int)rt));
                tg[42 + j] = inx - lf;
                tg[49 + j] = (inx >= 0.0f && inx <= fH) ? 1.0f : 0.0f;
            }
        }
        return;
    }
    const float* src; float* dst; int C, X, loc;
    if (bid < 1600)      { src = p2;  dst = T + T_P2;  C = 256; X = 25600; loc = bid; }
    else if (bid < 2000) { src = p3;  dst = T + T_P3;  C = 256; X = 6400;  loc = bid - 1600; }
    else if (bid < 2100) { src = p4;  dst = T + T_P4;  C = 256; X = 1600;  loc = bid - 2000; }
    else if (bid < 2128) { src = p5;  dst = T + T_P5;  C = 256; X = 400;   loc = bid - 2100; }
    else                 { src = rng; dst = T + T_RNG; C = 64;  X = 25600; loc = bid - 2128; }
    int xtiles = (X + 63) >> 6;
    int xt = loc % xtiles, ct = loc / xtiles;
    int x0 = xt << 6, c0 = ct << 6;
    #pragma unroll
    for (int r = 0; r < 16; r++) {
        int lin = r * 256 + t;
        int lc = lin >> 6, lx = lin & 63;
        int x = x0 + lx;
        tile[lc][lx] = (x < X) ? src[(size_t)(c0 + lc) * X + x] : 0.0f;
    }
    __syncthreads();
    #pragma unroll
    for (int r = 0; r < 16; r++) {
        int lin = r * 256 + t;
        int lxx = lin >> 6, lcc = lin & 63;
        int x = x0 + lxx;
        if (x < X) dst[(size_t)x * C + c0 + lcc] = tile[lcc][lxx];
    }
}

// ---------------- crop_and_resize from NHWC ----------------
#define RES_S 329
__global__ __launch_bounds__(256) void k_crop2(const float* __restrict__ T, const float* __restrict__ tab,
                                               float* __restrict__ out_rf, bf16* __restrict__ A) {
    int n = blockIdx.x, t = threadIdx.x;
    if (n >= NROIS) {                 // zero-pad A rows 1000..1023 (full padded row)
        i32x4* row = (i32x4*)(A + (size_t)n * KPAD);
        for (int i = t; i < KPAD * 2 / 16; i += 256) row[i] = i32x4{0,0,0,0};
        return;
    }
    __shared__ float res[49 * RES_S];
    __shared__ float tl_[TABS];
    if (t < TABS) tl_[t] = tab[(size_t)n * TABS + t];
    __syncthreads();
    int lvl = (int)tl_[112];
    int H = 160 >> (lvl - 2);
    int toff = (lvl == 2) ? T_P2 : (lvl == 3) ? T_P3 : (lvl == 4) ? T_P4 : T_P5;
    const float* F = T + toff;
    {
        int q = t & 63, pl = t >> 6, c4 = q * 4;
        for (int g = 0; g < 13; g++) {
            int pos = g * 4 + pl;
            if (pos < 49) {
                int i = pos / 7, j = pos % 7;
                int ti = (int)tl_[i],      bi = (int)tl_[7 + i];
                int li = (int)tl_[28 + j], ri = (int)tl_[35 + j];
                float ly = tl_[14 + i], lx = tl_[42 + j];
                float valid = tl_[21 + i] * tl_[49 + j];
                f32x4 vtl = *(const f32x4*)(F + (size_t)(ti * H + li) * 256 + c4);
                f32x4 vtr = *(const f32x4*)(F + (size_t)(ti * H + ri) * 256 + c4);
                f32x4 vbl = *(const f32x4*)(F + (size_t)(bi * H + li) * 256 + c4);
                f32x4 vbr = *(const f32x4*)(F + (size_t)(bi * H + ri) * 256 + c4);
                f32x4 top = vtl + (vtr - vtl) * lx;
                f32x4 bot = vbl + (vbr - vbl) * lx;
                f32x4 v = top + (bot - top) * ly;
                if (valid == 0.0f) v = f32x4{0.f,0.f,0.f,0.f};
                *(f32x4*)(&res[pos * RES_S + c4]) = v;
            }
        }
    }
    {
        int q = t & 15, pl = t >> 4, c4 = q * 4;
        const float* R = T + T_RNG;
        for (int g = 0; g < 4; g++) {
            int pos = g * 16 + pl;
            if (pos < 49) {
                int i = pos / 7, j = pos % 7;
                int ti = (int)tl_[56 + i], bi = (int)tl_[63 + i];
                int li = (int)tl_[84 + j], ri = (int)tl_[91 + j];
                float ly = tl_[70 + i], lx = tl_[98 + j];
                float valid = tl_[77 + i] * tl_[105 + j];
                f32x4 vtl = *(const f32x4*)(R + (size_t)(ti * 160 + li) * 64 + c4);
                f32x4 vtr = *(const f32x4*)(R + (size_t)(ti * 160 + ri) * 64 + c4);
                f32x4 vbl = *(const f32x4*)(R + (size_t)(bi * 160 + li) * 64 + c4);
                f32x4 vbr = *(const f32x4*)(R + (size_t)(bi * 160 + ri) * 64 + c4);
                f32x4 top = vtl + (vtr - vtl) * lx;
                f32x4 bot = vbl + (vbr - vbl) * lx;
                f32x4 v = top + (bot - top) * ly;
                if (valid == 0.0f) v = f32x4{0.f,0.f,0.f,0.f};
                *(f32x4*)(&res[pos * RES_S + 256 + c4]) = v;
            }
        }
    }
    __syncthreads();
    size_t ob = (size_t)n * KDIM;
    size_t ab = (size_t)n * KPAD;
    for (int k = 0; k < 31; k++) {
        int i2 = (k * 256 + t) * 2;
        if (i2 < KDIM) {
            float e0 = res[(i2 % 49) * RES_S + i2 / 49];
            int i3 = i2 + 1;
            float e1 = res[(i3 % 49) * RES_S + i3 / 49];
            *(f32x2*)(out_rf + ob + i2) = f32x2{e0, e1};
            bf16x2 b2; b2[0] = (bf16)e0; b2[1] = (bf16)e1;
            *(bf16x2*)(A + ab + i2) = b2;
        }
    }
    // zero K-pad cols [15680, 16128): 448 bf16 = 56 x 16B
    if (t < 56) ((i32x4*)(A + ab + KDIM))[t] = i32x4{0,0,0,0};
}

// ---------------- 256x256 8-phase MFMA GEMM, counted vmcnt, raw s_barrier ----------------
// A: bf16 [M x KA] via global_load_lds into [256][32] K-half regions (bank-balanced, no swizzle)
// B: f32  [N x KB] reg-staged 3 phases early -> cvt bf16 -> ds_write
// C = A * B^T -> part[z] (1024x1024 f32 slices). NT = K-tiles per block (even).
template<int REMAP>
__global__ __launch_bounds__(512, 2)
void k_gemm8p(const bf16* __restrict__ A, const float* __restrict__ Bf,
              float* __restrict__ part, const int KA, const int KB, const int NT) {
    __shared__ bf16 sA[2][2][8192];   // [buf][khalf][256*32]
    __shared__ bf16 sB[2][2][8192];
    int tid = threadIdx.x;
    int l = tid & 63, w = tid >> 6;
    int bx, by, bz;
    if (REMAP) {
        // 224 blocks: groups of 16 blocks sharing (z) co-located per XCD (first 8 groups exact)
        int id = blockIdx.x;
        int z, j;
        if (id < 128) { z = id & 7; j = id >> 3; }
        else { int r = id - 128; z = 8 + (r >> 4); j = r & 15; }
        bx = j & 3; by = j >> 2; bz = z;
    } else { bx = blockIdx.x; by = blockIdx.y; bz = blockIdx.z; }
    int tm = bx * 256, tn = by * 256;
    int t0 = bz * NT;
    const int maxT = KA / 64 - 1;

    int wr128 = (w >> 2) * 128;        // wave M-offset (2 rows of waves)
    int wc64  = (w & 3) * 64;          // wave N-offset (4 cols of waves)
    int lr = l & 15, lh8 = (l >> 4) * 8;

    // staging index: idx0 in [0,512); covers (row=idx0>>2, slot=idx0&3); q=1 adds 128 rows
    int idx0 = w * 64 + l;
    int ar0 = idx0 >> 2;
    int ac0 = (idx0 & 3) << 3;
    const bf16* Ab0 = A + (size_t)(tm + ar0) * KA + ac0;
    const bf16* Ab1 = A + (size_t)(tm + ar0 + 128) * KA + ac0;
    const float* Bb0 = Bf + (size_t)(tn + ar0) * KB;
    const float* Bb1 = Bf + (size_t)(tn + ar0 + 128) * KB;

    f32x4 acc[8][4] = {};
    f32x4 bqA0, bqA1, bqA2, bqA3, bqB0, bqB1, bqB2, bqB3;

#define GLLA(b_, s_, t_) do { int tt_ = min((t_), maxT); size_t kc_ = (size_t)tt_ * 64 + (s_) * 32; \
    __builtin_amdgcn_global_load_lds((const GAS void*)(Ab0 + kc_), (LAS void*)(&sA[b_][s_][idx0 * 8]), 16, 0, 0); \
    __builtin_amdgcn_global_load_lds((const GAS void*)(Ab1 + kc_), (LAS void*)(&sA[b_][s_][4096 + idx0 * 8]), 16, 0, 0); \
} while (0)

#define LOADB(S0, S1, S2, S3, t_, s_) do { int col_ = min((t_) * 64 + (s_) * 32 + ac0, KB - 8); \
    S0 = *(const f32x4*)(Bb0 + col_); S1 = *(const f32x4*)(Bb0 + col_ + 4); \
    S2 = *(const f32x4*)(Bb1 + col_); S3 = *(const f32x4*)(Bb1 + col_ + 4); \
} while (0)

#define WRITE_B(b_, s_, S0, S1, S2, S3) do { bf16x8 w0_, w1_; \
    _Pragma("unroll") for (int e_ = 0; e_ < 4; e_++) { \
        w0_[e_] = (bf16)S0[e_]; w0_[4 + e_] = (bf16)S1[e_]; \
        w1_[e_] = (bf16)S2[e_]; w1_[4 + e_] = (bf16)S3[e_]; } \
    *(bf16x8*)&sB[b_][s_][idx0 * 8] = w0_; \
    *(bf16x8*)&sB[b_][s_][4096 + idx0 * 8] = w1_; \
} while (0)

#define COMPUTE(b_, s_, nh_) do { bf16x8 af_[8], b0_, b1_; \
    _Pragma("unroll") for (int mf_ = 0; mf_ < 8; mf_++) \
        af_[mf_] = *(const bf16x8*)&sA[b_][s_][(wr128 + mf_ * 16 + lr) * 32 + lh8]; \
    b0_ = *(const bf16x8*)&sB[b_][s_][(wc64 + (nh_) * 32 + lr) * 32 + lh8]; \
    b1_ = *(const bf16x8*)&sB[b_][s_][(wc64 + (nh_) * 32 + 16 + lr) * 32 + lh8]; \
    __builtin_amdgcn_s_setprio(1); \
    _Pragma("unroll") for (int mf_ = 0; mf_ < 8; mf_++) { \
        acc[mf_][(nh_) * 2]     = __builtin_amdgcn_mfma_f32_16x16x32_bf16(af_[mf_], b0_, acc[mf_][(nh_) * 2], 0, 0, 0); \
        acc[mf_][(nh_) * 2 + 1] = __builtin_amdgcn_mfma_f32_16x16x32_bf16(af_[mf_], b1_, acc[mf_][(nh_) * 2 + 1], 0, 0, 0); } \
    __builtin_amdgcn_s_setprio(0); \
} while (0)

#define SYNCP() do { asm volatile("s_waitcnt vmcnt(6)" ::: "memory"); \
    asm volatile("s_waitcnt lgkmcnt(0)" ::: "memory"); \
    __builtin_amdgcn_s_barrier(); } while (0)

    // ---- prologue: stage t0 fully, preload t1 (B in regs, A in flight) ----
    LOADB(bqA0, bqA1, bqA2, bqA3, t0, 0);       // 4 loads  (t0.B0)
    GLLA(0, 0, t0);                             // 2        (t0.A0)
    LOADB(bqB0, bqB1, bqB2, bqB3, t0, 1);       // 4        (t0.B1)
    GLLA(0, 1, t0);                             // 2        (t0.A1)
    asm volatile("s_waitcnt vmcnt(8)" ::: "memory");
    WRITE_B(0, 0, bqA0, bqA1, bqA2, bqA3);
    asm volatile("s_waitcnt vmcnt(2)" ::: "memory");
    WRITE_B(0, 1, bqB0, bqB1, bqB2, bqB3);
    LOADB(bqA0, bqA1, bqA2, bqA3, t0 + 1, 0);   // 4        (t1.B0) -> written at ph1
    GLLA(1, 0, t0 + 1);                         // 2        (t1.A0)
    LOADB(bqB0, bqB1, bqB2, bqB3, t0 + 1, 1);   // 4        (t1.B1) -> written at ph3
    asm volatile("s_waitcnt lgkmcnt(0)" ::: "memory");
    __builtin_amdgcn_s_barrier();

    const int NI = NT >> 1;
    for (int i = 0; i < NI; i++) {
        int u = t0 + 2 * i;
        // ph1 (buf0, s0, nh0)
        SYNCP();
        WRITE_B(1, 0, bqA0, bqA1, bqA2, bqA3);  // (u+1).B0
        GLLA(1, 1, u + 1);                      // (u+1).A1
        COMPUTE(0, 0, 0);
        // ph2
        LOADB(bqA0, bqA1, bqA2, bqA3, u + 2, 0);
        COMPUTE(0, 0, 1);
        // ph3
        SYNCP();
        WRITE_B(1, 1, bqB0, bqB1, bqB2, bqB3);  // (u+1).B1
        GLLA(0, 0, u + 2);                      // (u+2).A0
        COMPUTE(0, 1, 0);
        // ph4
        LOADB(bqB0, bqB1, bqB2, bqB3, u + 2, 1);
        COMPUTE(0, 1, 1);
        // ph5
        SYNCP();
        WRITE_B(0, 0, bqA0, bqA1, bqA2, bqA3);  // (u+2).B0
        GLLA(0, 1, u + 2);                      // (u+2).A1
        COMPUTE(1, 0, 0);
        // ph6
        LOADB(bqA0, bqA1, bqA2, bqA3, u + 3, 0);
        COMPUTE(1, 0, 1);
        // ph7
        SYNCP();
        WRITE_B(0, 1, bqB0, bqB1, bqB2, bqB3);  // (u+2).B1
        GLLA(1, 0, u + 3);                      // (u+3).A0
        COMPUTE(1, 1, 0);
        // ph8
        LOADB(bqB0, bqB1, bqB2, bqB3, u + 3, 1);
        COMPUTE(1, 1, 1);
    }
#undef GLLA
#undef LOADB
#undef WRITE_B
#undef COMPUTE
#undef SYNCP

    float* pc = part + ((size_t)bz << 20);
    int lh4 = (l >> 4) * 4;
    #pragma unroll
    for (int mf = 0; mf < 8; mf++)
        #pragma unroll
        for (int nf = 0; nf < 4; nf++)
            #pragma unroll
            for (int r = 0; r < 4; r++)
                pc[(size_t)(tm + wr128 + mf * 16 + lh4 + r) * 1024 + (tn + wc64 + nf * 16 + lr)] = acc[mf][nf][r];
}

// ---------------- reduce split-K(14) + bias + BN + ReLU -> bf16 (x1) ----------------
__global__ void k_reduce1(const float* __restrict__ part, const float* __restrict__ bias,
                          const float* __restrict__ gam, const float* __restrict__ bet,
                          const float* __restrict__ mu, const float* __restrict__ var,
                          bf16* __restrict__ x1b) {
    int idx = blockIdx.x * 256 + threadIdx.x;
    int n = idx >> 8;
    int o = (idx & 255) << 2;
    f32x4 v = {};
    #pragma unroll
    for (int s = 0; s < 14; s++) v += *(const f32x4*)(part + ((size_t)s << 20) + (size_t)n * 1024 + o);
    f32x4 b4 = *(const f32x4*)(bias + o);
    f32x4 g4 = *(const f32x4*)(gam + o);
    f32x4 e4 = *(const f32x4*)(bet + o);
    f32x4 m4 = *(const f32x4*)(mu + o);
    f32x4 v4 = *(const f32x4*)(var + o);
    bf16x4 ov;
    #pragma unroll
    for (int e = 0; e < 4; e++) {
        float sc = g4[e] / sqrtf(v4[e] + 0.001f);
        float y = (v[e] + b4[e] - m4[e]) * sc + e4[e];
        y = fmaxf(y, 0.0f);
        if (n >= NROIS) y = 0.0f;
        ov[e] = (bf16)y;
    }
    *(bf16x4*)(x1b + (size_t)n * 1024 + o) = ov;
}

// ---------------- reduce split-K(4) + bias + BN + ReLU -> f32 (x2) ----------------
__global__ void k_reduce2(const float* __restrict__ part, const float* __restrict__ bias,
                          const float* __restrict__ gam, const float* __restrict__ bet,
                          const float* __restrict__ mu, const float* __restrict__ var,
                          float* __restrict__ x2) {
    int idx = blockIdx.x * 256 + threadIdx.x;
    int n = idx >> 8;
    int o = (idx & 255) << 2;
    f32x4 v = {};
    #pragma unroll
    for (int s = 0; s < 4; s++) v += *(const f32x4*)(part + ((size_t)s << 20) + (size_t)n * 1024 + o);
    f32x4 b4 = *(const f32x4*)(bias + o);
    f32x4 g4 = *(const f32x4*)(gam + o);
    f32x4 e4 = *(const f32x4*)(bet + o);
    f32x4 m4 = *(const f32x4*)(mu + o);
    f32x4 v4 = *(const f32x4*)(var + o);
    f32x4 ov;
    #pragma unroll
    for (int e = 0; e < 4; e++) {
        float sc = g4[e] / sqrtf(v4[e] + 0.001f);
        float y = (v[e] + b4[e] - m4[e]) * sc + e4[e];
        ov[e] = fmaxf(y, 0.0f);
    }
    *(f32x4*)(x2 + (size_t)n * 1024 + o) = ov;
}

// ---------------- heads ----------------
__device__ __forceinline__ float wred(float v) {
    #pragma unroll
    for (int off = 32; off; off >>= 1) v += __shfl_xor(v, off);
    return v;
}

__global__ void k_heads(const float* __restrict__ x2,
                        const float* __restrict__ wc, const float* __restrict__ bc,
                        const float* __restrict__ wb, const float* __restrict__ bb,
                        const float* __restrict__ wp, const float* __restrict__ bp,
                        float* __restrict__ out) {
    int w = threadIdx.x >> 6, l = threadIdx.x & 63;
    int n = blockIdx.x * 4 + w;
    float ac0 = 0.f, ac1 = 0.f, ab[8] = {}, ap[6] = {};
    const float* xr = x2 + (size_t)n * 1024;
    for (int kk = 0; kk < 16; kk++) {
        int k = kk * 64 + l;
        float xv = xr[k];
        ac0 += xv * wc[k];
        ac1 += xv * wc[1024 + k];
        #pragma unroll
        for (int o = 0; o < 8; o++) ab[o] += xv * wb[o * 1024 + k];
        #pragma unroll
        for (int o = 0; o < 6; o++) ap[o] += xv * wp[o * 1024 + k];
    }
    ac0 = wred(ac0); ac1 = wred(ac1);
    #pragma unroll
    for (int o = 0; o < 8; o++) ab[o] = wred(ab[o]);
    #pragma unroll
    for (int o = 0; o < 6; o++) ap[o] = wred(ap[o]);
    if (l == 0) {
        float l0 = ac0 + bc[0], l1 = ac1 + bc[1];
        out[n * 2] = l0; out[n * 2 + 1] = l1;
        float m = fmaxf(l0, l1);
        float e0 = expf(l0 - m), e1 = expf(l1 - m);
        float inv = 1.0f / (e0 + e1);
        out[2000 + n * 2] = e0 * inv; out[2000 + n * 2 + 1] = e1 * inv;
        #pragma unroll
        for (int o = 0; o < 8; o++) out[4000 + n * 8 + o] = ab[o] + bb[o];
        #pragma unroll
        for (int o = 0; o < 6; o++) out[12000 + n * 6 + o] = ap[o] + bp[o];
    }
}

extern "C" void kernel_launch(void* const* d_in, const int* in_sizes, int n_in,
                              void* d_out, int out_size, void* d_ws, size_t ws_size,
                              hipStream_t stream) {
    const float* p2      = (const float*)d_in[0];
    const float* p3      = (const float*)d_in[1];
    const float* p4      = (const float*)d_in[2];
    const float* p5      = (const float*)d_in[3];
    const float* rois    = (const float*)d_in[4];
    const float* ranges  = (const float*)d_in[5];
    const float* conv1_w = (const float*)d_in[6];
    const float* conv1_b = (const float*)d_in[7];
    const float* bn1_g   = (const float*)d_in[8];
    const float* bn1_b   = (const float*)d_in[9];
    const float* bn1_m   = (const float*)d_in[10];
    const float* bn1_v   = (const float*)d_in[11];
    const float* conv2_w = (const float*)d_in[12];
    const float* conv2_b = (const float*)d_in[13];
    const float* bn2_g   = (const float*)d_in[14];
    const float* bn2_b   = (const float*)d_in[15];
    const float* bn2_m   = (const float*)d_in[16];
    const float* bn2_v   = (const float*)d_in[17];
    const float* wc      = (const float*)d_in[18];
    const float* bc      = (const float*)d_in[19];
    const float* wb      = (const float*)d_in[20];
    const float* bb      = (const float*)d_in[21];
    const float* wp      = (const float*)d_in[22];
    const float* bp      = (const float*)d_in[23];

    char* ws = (char*)d_ws;
    bf16*  A    = (bf16*)(ws + OFF_A);
    float* part = (float*)(ws + OFF_PART);
    float* tab  = (float*)(ws + OFF_TAB);
    float* T    = (float*)(ws + OFF_T);
    bf16*  x1b  = (bf16*)(ws + OFF_X1B);
    float* x2   = (float*)(ws + OFF_X2);
    float* out  = (float*)d_out;

    k_prep<<<2532, 256, 0, stream>>>(p2, p3, p4, p5, ranges, T, rois, tab);
    k_crop2<<<1024, 256, 0, stream>>>(T, tab, out + 18000, A);
    // GEMM1: M=1024(pad) x N=1024 x K=16128(pad of 15680), 256x256 tiles, z=14, NT=18
    k_gemm8p<1><<<224, 512, 0, stream>>>(A, conv1_w, part, KPAD, KDIM, 18);
    k_reduce1<<<1024, 256, 0, stream>>>(part, conv1_b, bn1_g, bn1_b, bn1_m, bn1_v, x1b);
    // GEMM2: K=1024, z=4, NT=4
    k_gemm8p<0><<<dim3(4, 4, 4), 512, 0, stream>>>(x1b, conv2_w, part, 1024, 1024, 4);
    k_reduce2<<<1024, 256, 0, stream>>>(part, conv2_b, bn2_g, bn2_b, bn2_m, bn2_v, x2);
    k_heads<<<250, 256, 0, stream>>>(x2, wc, bc, wb, bb, wp, bp, out);
}